// Round 8
// baseline (580.286 us; speedup 1.0000x reference)
//
#include <hip/hip_runtime.h>
#include <stdint.h>

typedef unsigned short u16;
typedef _Float16 v8h __attribute__((ext_vector_type(8)));
typedef float v4f __attribute__((ext_vector_type(4)));

static __device__ __forceinline__ float h2f(u16 u) {
    union { u16 s; _Float16 h; } v; v.s = u; return (float)v.h;
}
static __device__ __forceinline__ u16 f2h(float f) {
    union { u16 s; _Float16 h; } v; v.h = (_Float16)f; return v.s;
}

// async global->LDS, 16B per lane. lds dest = wave-uniform base + lane*16.
static __device__ __forceinline__ void gload_lds16(const u16* g, const u16* l) {
    __builtin_amdgcn_global_load_lds(
        (const __attribute__((address_space(1))) uint32_t*)(uintptr_t)g,
        (__attribute__((address_space(3))) uint32_t*)(uintptr_t)l,
        16, 0, 0);
}

// ---------------- convert f32 -> f16, vectorized x8 ----------------
__global__ __launch_bounds__(256) void cvt_f16(const float* __restrict__ in,
                                               u16* __restrict__ out, int n8) {
    const int i = blockIdx.x * 256 + threadIdx.x;
    if (i >= n8) return;
    const float4 a = ((const float4*)in)[2 * i];
    const float4 b = ((const float4*)in)[2 * i + 1];
    u16 o[8] = {f2h(a.x), f2h(a.y), f2h(a.z), f2h(a.w),
                f2h(b.x), f2h(b.y), f2h(b.z), f2h(b.w)};
    *(uint4*)(out + (size_t)i * 8) = *(const uint4*)o;
}

// ---------------- all weight transposes f32 [R][C] -> f16 [C][R], one launch ----------------
__global__ __launch_bounds__(256) void transpose_all(
    const float* __restrict__ Wq, const float* __restrict__ Wk,
    const float* __restrict__ Wv, const float* __restrict__ Wo,
    const float* __restrict__ W1, const float* __restrict__ W2,
    u16* __restrict__ WqkT, u16* __restrict__ WvT, u16* __restrict__ WoT,
    u16* __restrict__ W1T, u16* __restrict__ W2T)
{
    int t = blockIdx.x;
    const float* in; u16* out; long ldi, ldo; int xt;
    if (t < 1024)      {            in = Wq; out = WqkT;              ldi = 1024; ldo = 1024; xt = 32; }
    else if (t < 2048) { t -= 1024; in = Wk; out = WqkT + 1024*1024;  ldi = 1024; ldo = 1024; xt = 32; }
    else if (t < 3072) { t -= 2048; in = Wv; out = WvT;               ldi = 1024; ldo = 1024; xt = 32; }
    else if (t < 4096) { t -= 3072; in = Wo; out = WoT;               ldi = 1024; ldo = 1024; xt = 32; }
    else if (t < 8192) { t -= 4096; in = W1; out = W1T;               ldi = 4096; ldo = 1024; xt = 128; }
    else               { t -= 8192; in = W2; out = W2T;               ldi = 1024; ldo = 4096; xt = 32; }
    const int c0 = (t % xt) * 32, r0 = (t / xt) * 32;
    __shared__ float tile[32][33];
    for (int i = threadIdx.y; i < 32; i += 8)
        tile[i][threadIdx.x] = in[(long)(r0 + i) * ldi + c0 + threadIdx.x];
    __syncthreads();
    for (int i = threadIdx.y; i < 32; i += 8)
        out[(long)(c0 + i) * ldo + r0 + threadIdx.x] = f2h(tile[threadIdx.x][i]);
}

// ======== f16 GEMM: C = A @ B^T (+bias)(+relu) ========
// OMODE: 0 = f16 out, 1 = f32 out, 2 = f16 transposed-batched out (C[b][col][row], b from m0)
// BIAS: 0 none, 1 single, 2 dual (bias for col<1024, bias2 for col>=1024)
// BK=64, XOR-swizzled LDS (conflict-free), 32 MFMA per barrier-pair.
// XCD swizzle: blocks sharing an A-tile land at linear stride 8 -> same XCD L2.
template<int OMODE, int BIAS, bool RELU>
__global__ __launch_bounds__(256) void gemm_f16(
    const u16* __restrict__ A, long lda, long Asb,
    const u16* __restrict__ B, long ldb, long Bsb,
    void* __restrict__ Cv, long ldc, long Csb,
    const float* __restrict__ bias, const float* __restrict__ bias2, int K)
{
    alignas(16) __shared__ u16 As[128 * 64];
    alignas(16) __shared__ u16 Bs[128 * 64];
    const int t = threadIdx.x;

    // ---- XCD-aware remap (bijection; requires gridDim.y*gridDim.z % 8 == 0) ----
    const int nx = gridDim.x, ny = gridDim.y;
    const long lin = blockIdx.x + (long)nx * (blockIdx.y + (long)gridDim.y * blockIdx.z);
    const int g = (int)(lin & 7);
    const long s = lin >> 3;
    const int xe = (int)(s % nx);
    const long w = g + 8 * (s / nx);
    const int ye = (int)(w % ny);
    const long b = w / ny;

    A += b * Asb; B += b * Bsb;
    const long m0 = (long)ye * 128;
    const long n0 = (long)xe * 128;
    const int lane = t & 63, wave = t >> 6;
    const int wm = (wave >> 1) * 64, wn = (wave & 1) * 64;
    const int l16 = lane & 15, quad = lane >> 4;

    const int rr = t >> 3;                           // 0..31
    const int cg8 = ((t & 7) ^ ((t >> 3) & 7)) * 8;  // lane-permuted col (elts)
    const int wv512 = wave * 512;

    // hoisted per-thread global element offsets (k0 stays uniform/scalar)
    long aofs[4], bofs[4];
#pragma unroll
    for (int p = 0; p < 4; ++p) {
        aofs[p] = (m0 + p * 32 + rr) * lda + cg8;
        bofs[p] = (n0 + p * 32 + rr) * ldb + cg8;
    }

    v4f acc[4][4];
#pragma unroll
    for (int i = 0; i < 4; ++i)
#pragma unroll
        for (int j = 0; j < 4; ++j)
            acc[i][j] = (v4f){0.f, 0.f, 0.f, 0.f};

    for (int k0 = 0; k0 < K; k0 += 64) {
        __syncthreads();
#pragma unroll
        for (int p = 0; p < 4; ++p) {
            gload_lds16(A + aofs[p] + k0, As + p * 2048 + wv512);
            gload_lds16(B + bofs[p] + k0, Bs + p * 2048 + wv512);
        }
        __syncthreads();

#pragma unroll
        for (int kk = 0; kk < 2; ++kk) {
            const int swz = ((kk * 4 + quad) ^ (l16 & 7)) * 8;
            v8h af[4], bfr[4];
#pragma unroll
            for (int i = 0; i < 4; ++i)
                af[i] = *(const v8h*)&As[(wm + i * 16 + l16) * 64 + swz];
#pragma unroll
            for (int j = 0; j < 4; ++j)
                bfr[j] = *(const v8h*)&Bs[(wn + j * 16 + l16) * 64 + swz];
#pragma unroll
            for (int i = 0; i < 4; ++i)
#pragma unroll
                for (int j = 0; j < 4; ++j)
                    acc[i][j] = __builtin_amdgcn_mfma_f32_16x16x32_f16(af[i], bfr[j], acc[i][j], 0, 0, 0);
        }
    }

    // per-j bias
    float bv[4];
#pragma unroll
    for (int j = 0; j < 4; ++j) {
        const long col = n0 + wn + j * 16 + l16;
        bv[j] = (BIAS == 0) ? 0.f
              : (BIAS == 1) ? bias[col]
              : (col < 1024 ? bias[col] : bias2[col - 1024]);
    }

    if (OMODE == 2) {
        // transposed write: C[b][col][row], batch derived from m0 (batch rows = 2048)
        const long bb = m0 >> 11, mb = m0 & 2047;
        u16* C = (u16*)Cv + bb * Csb;
#pragma unroll
        for (int j = 0; j < 4; ++j) {
            const long col = n0 + wn + j * 16 + l16;
            u16* pc = C + col * ldc + mb + wm + quad * 4;
#pragma unroll
            for (int i = 0; i < 4; ++i) {
                u16 o[4];
#pragma unroll
                for (int r = 0; r < 4; ++r) {
                    float val = acc[i][j][r] + bv[j];
                    if (RELU) val = fmaxf(val, 0.f);
                    o[r] = f2h(val);
                }
                *(uint2*)(pc + i * 16) = *(const uint2*)o;
            }
        }
    } else {
        const long cb = b * Csb + (m0 + wm + quad * 4) * ldc + (n0 + wn + l16);
        if (OMODE == 1) {
            float* p0 = (float*)Cv + cb;
#pragma unroll
            for (int i = 0; i < 4; ++i)
#pragma unroll
                for (int r = 0; r < 4; ++r) {
                    float* prow = p0 + (long)(i * 16 + r) * ldc;
#pragma unroll
                    for (int j = 0; j < 4; ++j) {
                        float val = acc[i][j][r] + bv[j];
                        if (RELU) val = fmaxf(val, 0.f);
                        prow[j * 16] = val;
                    }
                }
        } else {
            u16* p0 = (u16*)Cv + cb;
#pragma unroll
            for (int i = 0; i < 4; ++i)
#pragma unroll
                for (int r = 0; r < 4; ++r) {
                    u16* prow = p0 + (long)(i * 16 + r) * ldc;
#pragma unroll
                    for (int j = 0; j < 4; ++j) {
                        float val = acc[i][j][r] + bv[j];
                        if (RELU) val = fmaxf(val, 0.f);
                        prow[j * 16] = f2h(val);
                    }
                }
        }
    }
}

// ---------------- softmax over f32 rows of 2048 -> f16 P in-place at row start ----------------
__global__ __launch_bounds__(256) void softmax_rows(float* __restrict__ S) {
    const long row = blockIdx.x;
    float* p = S + row * 2048;
    const int t = threadIdx.x;
    float v[8];
    float mx = -1e30f;
#pragma unroll
    for (int i = 0; i < 8; ++i) { v[i] = p[t + i * 256]; mx = fmaxf(mx, v[i]); }
    __shared__ float red[256];
    red[t] = mx; __syncthreads();
    for (int off = 128; off > 0; off >>= 1) {
        if (t < off) red[t] = fmaxf(red[t], red[t + off]);
        __syncthreads();
    }
    mx = red[0]; __syncthreads();
    float sum = 0.f;
#pragma unroll
    for (int i = 0; i < 8; ++i) { v[i] = __expf(v[i] - mx); sum += v[i]; }
    red[t] = sum; __syncthreads();
    for (int off = 128; off > 0; off >>= 1) {
        if (t < off) red[t] += red[t + off];
        __syncthreads();
    }
    const float inv = 1.f / red[0];
    u16* q = (u16*)p;
#pragma unroll
    for (int i = 0; i < 8; ++i) q[t + i * 256] = f2h(v[i] * inv);
}

// ---------------- ln1: x = LN(src_f32 + attnO_f16); writes f32 and f16 ----------------
__global__ __launch_bounds__(256) void ln_dual(
    const float* __restrict__ a, const u16* __restrict__ bb,
    const float* __restrict__ g, const float* __restrict__ be,
    float* __restrict__ out32, u16* __restrict__ out16)
{
    const long base = (long)blockIdx.x * 1024;
    const int t = threadIdx.x;
    float v[4]; float s = 0.f, ss = 0.f;
#pragma unroll
    for (int i = 0; i < 4; ++i) {
        const int c = t + i * 256;
        const float x = a[base + c] + h2f(bb[base + c]);
        v[i] = x; s += x; ss += x * x;
    }
    __shared__ float rs[256], rss[256];
    rs[t] = s; rss[t] = ss; __syncthreads();
    for (int off = 128; off > 0; off >>= 1) {
        if (t < off) { rs[t] += rs[t + off]; rss[t] += rss[t + off]; }
        __syncthreads();
    }
    const float mean = rs[0] * (1.f / 1024.f);
    const float var = rss[0] * (1.f / 1024.f) - mean * mean;
    const float rstd = rsqrtf(var + 1e-5f);
#pragma unroll
    for (int i = 0; i < 4; ++i) {
        const int c = t + i * 256;
        const float y = (v[i] - mean) * rstd * g[c] + be[c];
        out32[base + c] = y;
        out16[base + c] = f2h(y);
    }
}

// ---------------- ln2: out_f32 = LN(x_f32 + ffO_f16) ----------------
__global__ __launch_bounds__(256) void ln_mix(
    const float* __restrict__ a, const u16* __restrict__ bb,
    const float* __restrict__ g, const float* __restrict__ be,
    float* __restrict__ out)
{
    const long base = (long)blockIdx.x * 1024;
    const int t = threadIdx.x;
    float v[4]; float s = 0.f, ss = 0.f;
#pragma unroll
    for (int i = 0; i < 4; ++i) {
        const int c = t + i * 256;
        const float x = a[base + c] + h2f(bb[base + c]);
        v[i] = x; s += x; ss += x * x;
    }
    __shared__ float rs[256], rss[256];
    rs[t] = s; rss[t] = ss; __syncthreads();
    for (int off = 128; off > 0; off >>= 1) {
        if (t < off) { rs[t] += rs[t + off]; rss[t] += rss[t + off]; }
        __syncthreads();
    }
    const float mean = rs[0] * (1.f / 1024.f);
    const float var = rss[0] * (1.f / 1024.f) - mean * mean;
    const float rstd = rsqrtf(var + 1e-5f);
#pragma unroll
    for (int i = 0; i < 4; ++i) {
        const int c = t + i * 256;
        out[base + c] = (v[i] - mean) * rstd * g[c] + be[c];
    }
}

extern "C" void kernel_launch(void* const* d_in, const int* in_sizes, int n_in,
                              void* d_out, int out_size, void* d_ws, size_t ws_size,
                              hipStream_t stream) {
    (void)in_sizes; (void)n_in; (void)out_size; (void)ws_size;
    constexpr long S = 2048, E = 1024, F = 4096, M = 8192;

    const float* src = (const float*)d_in[0];
    const float* Wq  = (const float*)d_in[1];
    const float* bq  = (const float*)d_in[2];
    const float* Wk  = (const float*)d_in[3];
    const float* bk  = (const float*)d_in[4];
    const float* Wv  = (const float*)d_in[5];
    const float* bv  = (const float*)d_in[6];
    const float* Wo  = (const float*)d_in[7];
    const float* bo  = (const float*)d_in[8];
    const float* W1  = (const float*)d_in[9];
    const float* b1  = (const float*)d_in[10];
    const float* W2  = (const float*)d_in[11];
    const float* b2  = (const float*)d_in[12];
    const float* g1  = (const float*)d_in[13];
    const float* be1 = (const float*)d_in[14];
    const float* g2  = (const float*)d_in[15];
    const float* be2 = (const float*)d_in[16];

    char* ws = (char*)d_ws;
    size_t off = 0;
    auto take = [&](size_t bytes) {
        char* p = ws + off;
        off += (bytes + 255) & ~(size_t)255;
        return p;
    };
    const size_t MB16 = 16777216;  // f16 [8192][1024]
    u16*   srcH  = (u16*)take(MB16);
    u16*   WqkT  = (u16*)take(2 * E * E * 2);     // [2048][1024]: WqT | WkT
    u16*   WvT   = (u16*)take(E * E * 2);
    u16*   WoT   = (u16*)take(E * E * 2);
    u16*   W1T   = (u16*)take(F * E * 2);         // [4096][1024]
    u16*   W2T   = (u16*)take(E * F * 2);         // [1024][4096]
    char*  B0    = take(2 * MB16);                // QK f16 [8192][2048] -> x32 f32
    char*  B1    = take(MB16);                    // VT f16 [4][1024][2048]
    char*  B2    = take(4ull * S * S * 4);        // Sf f32 (P f16 in-place) -> hf f16 [8192][4096]
    char*  B3    = take(MB16);                    // attn f16 -> xh f16
    char*  B4    = take(MB16);                    // attnO f16 -> ffO f16

    u16*   QK    = (u16*)B0;
    float* x32   = (float*)B0;
    u16*   VT    = (u16*)B1;
    float* Sf    = (float*)B2;
    u16*   hf    = (u16*)B2;
    u16*   attn  = (u16*)B3;
    u16*   xh    = (u16*)B3;
    u16*   attnO = (u16*)B4;
    u16*   ffO   = (u16*)B4;

    dim3 blk(256), tb(32, 8);

    // 1) convert src -> f16
    cvt_f16<<<dim3(M * E / 8 / 256), blk, 0, stream>>>(src, srcH, M * E / 8);

    // 2) all weight transposes in one launch
    transpose_all<<<dim3(12288), tb, 0, stream>>>(Wq, Wk, Wv, Wo, W1, W2,
                                                  WqkT, WvT, WoT, W1T, W2T);

    // 3) merged Q|K projection: QK [8192][2048] f16 (dual bias)
    gemm_f16<0, 2, false><<<dim3(16, 64, 1), blk, 0, stream>>>(
        srcH, E, 0, WqkT, E, 0, QK, 2 * E, 0, bq, bk, E);

    // 4) V projection with transposed write: VT[b][col][row]
    gemm_f16<2, 1, false><<<dim3(8, 64, 1), blk, 0, stream>>>(
        srcH, E, 0, WvT, E, 0, VT, S, E * S, bv, nullptr, E);

    // 5) scores[b] = Q[b] @ K[b]^T (f32 out)
    gemm_f16<1, 0, false><<<dim3(16, 16, 4), blk, 0, stream>>>(
        QK, 2 * E, S * 2 * E, QK + E, 2 * E, S * 2 * E,
        Sf, S, S * S, nullptr, nullptr, E);

    // 6) softmax (f32 in, f16 P in-place, row pitch 4096 halves)
    softmax_rows<<<dim3(M), blk, 0, stream>>>(Sf);

    // 7) attn[b] = P[b] @ V[b]
    gemm_f16<0, 0, false><<<dim3(8, 16, 4), blk, 0, stream>>>(
        (const u16*)Sf, 2 * S, S * 2 * S, VT, S, E * S,
        attn, E, S * E, nullptr, nullptr, S);

    // 8) attnO = attn @ Wo + bo (f16)
    gemm_f16<0, 1, false><<<dim3(8, 64, 1), blk, 0, stream>>>(
        attn, E, 0, WoT, E, 0, attnO, E, 0, bo, nullptr, E);

    // 9) x = LN(src + attnO) -> x32 (f32, over dead QK) and xh (f16, over dead attn)
    ln_dual<<<dim3(M), blk, 0, stream>>>(src, attnO, g1, be1, x32, xh);

    // 10) hf = relu(xh @ W1 + b1) (f16, over dead Sf/P)
    gemm_f16<0, 1, true><<<dim3(32, 64, 1), blk, 0, stream>>>(
        xh, E, 0, W1T, E, 0, hf, F, 0, b1, nullptr, E);

    // 11) ffO = hf @ W2 + b2 (f16, over dead attnO)
    gemm_f16<0, 1, false><<<dim3(8, 64, 1), blk, 0, stream>>>(
        hf, F, 0, W2T, F, 0, ffO, E, 0, b2, nullptr, F);

    // 12) out = LN(x32 + ffO) -> f32
    ln_mix<<<dim3(M), blk, 0, stream>>>(x32, ffO, g2, be2, (float*)d_out);
}

// Round 9
// 567.821 us; speedup vs baseline: 1.0220x; 1.0220x over previous
//
#include <hip/hip_runtime.h>
#include <stdint.h>

typedef unsigned short u16;
typedef _Float16 v8h __attribute__((ext_vector_type(8)));
typedef float v4f __attribute__((ext_vector_type(4)));

static __device__ __forceinline__ float h2f(u16 u) {
    union { u16 s; _Float16 h; } v; v.s = u; return (float)v.h;
}
static __device__ __forceinline__ u16 f2h(float f) {
    union { u16 s; _Float16 h; } v; v.h = (_Float16)f; return v.s;
}

// async global->LDS, 16B per lane. lds dest = wave-uniform base + lane*16.
static __device__ __forceinline__ void gload_lds16(const u16* g, const u16* l) {
    __builtin_amdgcn_global_load_lds(
        (const __attribute__((address_space(1))) uint32_t*)(uintptr_t)g,
        (__attribute__((address_space(3))) uint32_t*)(uintptr_t)l,
        16, 0, 0);
}

// ---------------- convert f32 -> f16, vectorized x8 ----------------
__global__ __launch_bounds__(256) void cvt_f16(const float* __restrict__ in,
                                               u16* __restrict__ out, int n8) {
    const int i = blockIdx.x * 256 + threadIdx.x;
    if (i >= n8) return;
    const float4 a = ((const float4*)in)[2 * i];
    const float4 b = ((const float4*)in)[2 * i + 1];
    u16 o[8] = {f2h(a.x), f2h(a.y), f2h(a.z), f2h(a.w),
                f2h(b.x), f2h(b.y), f2h(b.z), f2h(b.w)};
    *(uint4*)(out + (size_t)i * 8) = *(const uint4*)o;
}

// ---------------- all weight transposes f32 [R][C] -> f16 [C][R], one launch ----------------
__global__ __launch_bounds__(256) void transpose_all(
    const float* __restrict__ Wq, const float* __restrict__ Wk,
    const float* __restrict__ Wv, const float* __restrict__ Wo,
    const float* __restrict__ W1, const float* __restrict__ W2,
    u16* __restrict__ WqkvT, u16* __restrict__ WoT,
    u16* __restrict__ W1T, u16* __restrict__ W2T)
{
    int t = blockIdx.x;
    const float* in; u16* out; long ldi, ldo; int xt;
    if (t < 1024)      {            in = Wq; out = WqkvT;               ldi = 1024; ldo = 1024; xt = 32; }
    else if (t < 2048) { t -= 1024; in = Wk; out = WqkvT + 1024*1024;   ldi = 1024; ldo = 1024; xt = 32; }
    else if (t < 3072) { t -= 2048; in = Wv; out = WqkvT + 2*1024*1024; ldi = 1024; ldo = 1024; xt = 32; }
    else if (t < 4096) { t -= 3072; in = Wo; out = WoT;                 ldi = 1024; ldo = 1024; xt = 32; }
    else if (t < 8192) { t -= 4096; in = W1; out = W1T;                 ldi = 4096; ldo = 1024; xt = 128; }
    else               { t -= 8192; in = W2; out = W2T;                 ldi = 1024; ldo = 4096; xt = 32; }
    const int c0 = (t % xt) * 32, r0 = (t / xt) * 32;
    __shared__ float tile[32][33];
    for (int i = threadIdx.y; i < 32; i += 8)
        tile[i][threadIdx.x] = in[(long)(r0 + i) * ldi + c0 + threadIdx.x];
    __syncthreads();
    for (int i = threadIdx.y; i < 32; i += 8)
        out[(long)(c0 + i) * ldo + r0 + threadIdx.x] = f2h(tile[threadIdx.x][i]);
}

// ======== f16 GEMM: C = A @ B^T (+bias)(+relu) ========
// OMODE: 0 = f16 out
//        3 = QKV mode: n0<2048 -> normal f16 write to C0 (ldc); n0>=2048 -> transposed
//            batched write to C1: C1[b][col-2048][row], b = m0>>11 (batch rows 2048)
// BIAS: 0 none, 1 single, 3 triple (col>>10 selects bias/bias2/bias3)
// BK=64, XOR-swizzled LDS (conflict-free), 32 MFMA per barrier-pair.
template<int OMODE, int BIAS, bool RELU>
__global__ __launch_bounds__(256) void gemm_f16(
    const u16* __restrict__ A, long lda, long Asb,
    const u16* __restrict__ B, long ldb, long Bsb,
    void* __restrict__ Cv, long ldc, long Csb, u16* __restrict__ C1,
    const float* __restrict__ bias, const float* __restrict__ bias2,
    const float* __restrict__ bias3, int K)
{
    alignas(16) __shared__ u16 As[128 * 64];
    alignas(16) __shared__ u16 Bs[128 * 64];
    const int t = threadIdx.x;
    const long b = blockIdx.z;
    A += b * Asb; B += b * Bsb;
    const long m0 = (long)blockIdx.y * 128;
    const long n0 = (long)blockIdx.x * 128;
    const int lane = t & 63, wave = t >> 6;
    const int wm = (wave >> 1) * 64, wn = (wave & 1) * 64;
    const int l16 = lane & 15, quad = lane >> 4;

    const int rr = t >> 3;                           // 0..31
    const int cg8 = ((t & 7) ^ ((t >> 3) & 7)) * 8;  // lane-permuted col (elts)
    const int wv512 = wave * 512;

    // hoisted per-thread global element offsets (k0 stays uniform/scalar)
    long aofs[4], bofs[4];
#pragma unroll
    for (int p = 0; p < 4; ++p) {
        aofs[p] = (m0 + p * 32 + rr) * lda + cg8;
        bofs[p] = (n0 + p * 32 + rr) * ldb + cg8;
    }

    v4f acc[4][4];
#pragma unroll
    for (int i = 0; i < 4; ++i)
#pragma unroll
        for (int j = 0; j < 4; ++j)
            acc[i][j] = (v4f){0.f, 0.f, 0.f, 0.f};

    for (int k0 = 0; k0 < K; k0 += 64) {
        __syncthreads();
#pragma unroll
        for (int p = 0; p < 4; ++p) {
            gload_lds16(A + aofs[p] + k0, As + p * 2048 + wv512);
            gload_lds16(B + bofs[p] + k0, Bs + p * 2048 + wv512);
        }
        __syncthreads();

#pragma unroll
        for (int kk = 0; kk < 2; ++kk) {
            const int swz = ((kk * 4 + quad) ^ (l16 & 7)) * 8;
            v8h af[4], bfr[4];
#pragma unroll
            for (int i = 0; i < 4; ++i)
                af[i] = *(const v8h*)&As[(wm + i * 16 + l16) * 64 + swz];
#pragma unroll
            for (int j = 0; j < 4; ++j)
                bfr[j] = *(const v8h*)&Bs[(wn + j * 16 + l16) * 64 + swz];
#pragma unroll
            for (int i = 0; i < 4; ++i)
#pragma unroll
                for (int j = 0; j < 4; ++j)
                    acc[i][j] = __builtin_amdgcn_mfma_f32_16x16x32_f16(af[i], bfr[j], acc[i][j], 0, 0, 0);
        }
    }

    // per-j bias
    float bv[4];
#pragma unroll
    for (int j = 0; j < 4; ++j) {
        const long col = n0 + wn + j * 16 + l16;
        if (BIAS == 0) bv[j] = 0.f;
        else if (BIAS == 1) bv[j] = bias[col];
        else {
            const int sel = (int)(col >> 10);
            const float* bp = sel == 0 ? bias : (sel == 1 ? bias2 : bias3);
            bv[j] = bp[col & 1023];
        }
    }

    if (OMODE == 3 && n0 >= 2048) {
        // transposed write: C1[b][col-2048][row], batch from m0 (batch rows = 2048)
        const long bb = m0 >> 11, mb = m0 & 2047;
        u16* C = C1 + bb * Csb;
#pragma unroll
        for (int j = 0; j < 4; ++j) {
            const long col = n0 - 2048 + wn + j * 16 + l16;
            u16* pc = C + col * 2048 + mb + wm + quad * 4;
#pragma unroll
            for (int i = 0; i < 4; ++i) {
                u16 o[4];
#pragma unroll
                for (int r = 0; r < 4; ++r) {
                    float val = acc[i][j][r] + bv[j];
                    if (RELU) val = fmaxf(val, 0.f);
                    o[r] = f2h(val);
                }
                *(uint2*)(pc + i * 16) = *(const uint2*)o;
            }
        }
    } else {
        const long cb = b * ((OMODE == 3) ? 0 : Csb) + (m0 + wm + quad * 4) * ldc + (n0 + wn + l16);
        u16* p0 = (u16*)Cv + cb;
#pragma unroll
        for (int i = 0; i < 4; ++i)
#pragma unroll
            for (int r = 0; r < 4; ++r) {
                u16* prow = p0 + (long)(i * 16 + r) * ldc;
#pragma unroll
                for (int j = 0; j < 4; ++j) {
                    float val = acc[i][j][r] + bv[j];
                    if (RELU) val = fmaxf(val, 0.f);
                    prow[j * 16] = f2h(val);
                }
            }
    }
}

// ---------------- softmax over f16 rows of 2048, in place ----------------
__global__ __launch_bounds__(256) void softmax_rows(u16* __restrict__ S) {
    const long row = blockIdx.x;
    u16* p = S + row * 2048;
    const int t = threadIdx.x;
    float v[8];
    float mx = -1e30f;
#pragma unroll
    for (int i = 0; i < 8; ++i) { v[i] = h2f(p[t + i * 256]); mx = fmaxf(mx, v[i]); }
    __shared__ float red[256];
    red[t] = mx; __syncthreads();
    for (int off = 128; off > 0; off >>= 1) {
        if (t < off) red[t] = fmaxf(red[t], red[t + off]);
        __syncthreads();
    }
    mx = red[0]; __syncthreads();
    float sum = 0.f;
#pragma unroll
    for (int i = 0; i < 8; ++i) { v[i] = __expf(v[i] - mx); sum += v[i]; }
    red[t] = sum; __syncthreads();
    for (int off = 128; off > 0; off >>= 1) {
        if (t < off) red[t] += red[t + off];
        __syncthreads();
    }
    const float inv = 1.f / red[0];
#pragma unroll
    for (int i = 0; i < 8; ++i) p[t + i * 256] = f2h(v[i] * inv);
}

// ---------------- ln1: xh_f16 = LN(src_f32 + attnO_f16) ----------------
__global__ __launch_bounds__(256) void ln_one(
    const float* __restrict__ a, const u16* __restrict__ bb,
    const float* __restrict__ g, const float* __restrict__ be,
    u16* __restrict__ out16)
{
    const long base = (long)blockIdx.x * 1024;
    const int t = threadIdx.x;
    float v[4]; float s = 0.f, ss = 0.f;
#pragma unroll
    for (int i = 0; i < 4; ++i) {
        const int c = t + i * 256;
        const float x = a[base + c] + h2f(bb[base + c]);
        v[i] = x; s += x; ss += x * x;
    }
    __shared__ float rs[256], rss[256];
    rs[t] = s; rss[t] = ss; __syncthreads();
    for (int off = 128; off > 0; off >>= 1) {
        if (t < off) { rs[t] += rs[t + off]; rss[t] += rss[t + off]; }
        __syncthreads();
    }
    const float mean = rs[0] * (1.f / 1024.f);
    const float var = rss[0] * (1.f / 1024.f) - mean * mean;
    const float rstd = rsqrtf(var + 1e-5f);
#pragma unroll
    for (int i = 0; i < 4; ++i) {
        const int c = t + i * 256;
        out16[base + c] = f2h((v[i] - mean) * rstd * g[c] + be[c]);
    }
}

// ---------------- ln2: out_f32 = LN(xh_f16 + ffO_f16) ----------------
__global__ __launch_bounds__(256) void ln_two(
    const u16* __restrict__ a, const u16* __restrict__ bb,
    const float* __restrict__ g, const float* __restrict__ be,
    float* __restrict__ out)
{
    const long base = (long)blockIdx.x * 1024;
    const int t = threadIdx.x;
    float v[4]; float s = 0.f, ss = 0.f;
#pragma unroll
    for (int i = 0; i < 4; ++i) {
        const int c = t + i * 256;
        const float x = h2f(a[base + c]) + h2f(bb[base + c]);
        v[i] = x; s += x; ss += x * x;
    }
    __shared__ float rs[256], rss[256];
    rs[t] = s; rss[t] = ss; __syncthreads();
    for (int off = 128; off > 0; off >>= 1) {
        if (t < off) { rs[t] += rs[t + off]; rss[t] += rss[t + off]; }
        __syncthreads();
    }
    const float mean = rs[0] * (1.f / 1024.f);
    const float var = rss[0] * (1.f / 1024.f) - mean * mean;
    const float rstd = rsqrtf(var + 1e-5f);
#pragma unroll
    for (int i = 0; i < 4; ++i) {
        const int c = t + i * 256;
        out[base + c] = (v[i] - mean) * rstd * g[c] + be[c];
    }
}

extern "C" void kernel_launch(void* const* d_in, const int* in_sizes, int n_in,
                              void* d_out, int out_size, void* d_ws, size_t ws_size,
                              hipStream_t stream) {
    (void)in_sizes; (void)n_in; (void)out_size; (void)ws_size;
    constexpr long S = 2048, E = 1024, F = 4096, M = 8192;

    const float* src = (const float*)d_in[0];
    const float* Wq  = (const float*)d_in[1];
    const float* bq  = (const float*)d_in[2];
    const float* Wk  = (const float*)d_in[3];
    const float* bk  = (const float*)d_in[4];
    const float* Wv  = (const float*)d_in[5];
    const float* bv  = (const float*)d_in[6];
    const float* Wo  = (const float*)d_in[7];
    const float* bo  = (const float*)d_in[8];
    const float* W1  = (const float*)d_in[9];
    const float* b1  = (const float*)d_in[10];
    const float* W2  = (const float*)d_in[11];
    const float* b2  = (const float*)d_in[12];
    const float* g1  = (const float*)d_in[13];
    const float* be1 = (const float*)d_in[14];
    const float* g2  = (const float*)d_in[15];
    const float* be2 = (const float*)d_in[16];

    char* ws = (char*)d_ws;
    size_t off = 0;
    auto take = [&](size_t bytes) {
        char* p = ws + off;
        off += (bytes + 255) & ~(size_t)255;
        return p;
    };
    const size_t MB16 = 16777216;  // f16 [8192][1024]
    u16*   srcH  = (u16*)take(MB16);
    u16*   WqkvT = (u16*)take(3 * E * E * 2);     // [3072][1024]: WqT | WkT | WvT
    u16*   WoT   = (u16*)take(E * E * 2);
    u16*   W1T   = (u16*)take(F * E * 2);         // [4096][1024]
    u16*   W2T   = (u16*)take(E * F * 2);         // [1024][4096]
    char*  B0    = take(2 * MB16);                // QK f16 [8192][2048]
    char*  B1    = take(MB16);                    // VT f16 [4][1024][2048]
    char*  B2    = take(4ull * S * S * 4);        // Sh f16 [4][2048][2048] (32M) -> hf f16 [8192][4096] (64M)
    char*  B3    = take(MB16);                    // attn f16 -> xh f16
    char*  B4    = take(MB16);                    // attnO f16 -> ffO f16

    u16*   QK    = (u16*)B0;
    u16*   VT    = (u16*)B1;
    u16*   Sh    = (u16*)B2;
    u16*   hf    = (u16*)B2;
    u16*   attn  = (u16*)B3;
    u16*   xh    = (u16*)B3;
    u16*   attnO = (u16*)B4;
    u16*   ffO   = (u16*)B4;

    dim3 blk(256), tb(32, 8);

    // 1) convert src -> f16
    cvt_f16<<<dim3(M * E / 8 / 256), blk, 0, stream>>>(src, srcH, M * E / 8);

    // 2) all weight transposes in one launch
    transpose_all<<<dim3(12288), tb, 0, stream>>>(Wq, Wk, Wv, Wo, W1, W2,
                                                  WqkvT, WoT, W1T, W2T);

    // 3) merged Q|K|V projection: QK [8192][2048] f16 + VT[b][col][row] (1536 blocks)
    gemm_f16<3, 3, false><<<dim3(24, 64, 1), blk, 0, stream>>>(
        srcH, E, 0, WqkvT, E, 0, QK, 2 * E, E * S, VT, bq, bk, bv, E);

    // 4) scores[b] = Q[b] @ K[b]^T (f16 out, ld 2048)
    gemm_f16<0, 0, false><<<dim3(16, 16, 4), blk, 0, stream>>>(
        QK, 2 * E, S * 2 * E, QK + E, 2 * E, S * 2 * E,
        Sh, S, S * S, nullptr, nullptr, nullptr, nullptr, E);

    // 5) softmax in place (f16)
    softmax_rows<<<dim3(M), blk, 0, stream>>>(Sh);

    // 6) attn[b] = P[b] @ V[b]
    gemm_f16<0, 0, false><<<dim3(8, 16, 4), blk, 0, stream>>>(
        Sh, S, S * S, VT, S, E * S,
        attn, E, S * E, nullptr, nullptr, nullptr, nullptr, S);

    // 7) attnO = attn @ Wo + bo (f16)
    gemm_f16<0, 1, false><<<dim3(8, 64, 1), blk, 0, stream>>>(
        attn, E, 0, WoT, E, 0, attnO, E, 0, nullptr, bo, nullptr, nullptr, E);

    // 8) xh = LN(src + attnO) (f16, over dead attn)
    ln_one<<<dim3(M), blk, 0, stream>>>(src, attnO, g1, be1, xh);

    // 9) hf = relu(xh @ W1 + b1) (f16, over dead Sh/P)
    gemm_f16<0, 1, true><<<dim3(32, 64, 1), blk, 0, stream>>>(
        xh, E, 0, W1T, E, 0, hf, F, 0, nullptr, b1, nullptr, nullptr, E);

    // 10) ffO = hf @ W2 + b2 (f16, over dead attnO)
    gemm_f16<0, 1, false><<<dim3(8, 64, 1), blk, 0, stream>>>(
        hf, F, 0, W2T, F, 0, ffO, E, 0, nullptr, b2, nullptr, nullptr, F);

    // 11) out = LN(xh + ffO) -> f32
    ln_two<<<dim3(M), blk, 0, stream>>>(xh, ffO, g2, be2, (float*)d_out);
}

// Round 10
// 552.940 us; speedup vs baseline: 1.0495x; 1.0269x over previous
//
#include <hip/hip_runtime.h>
#include <stdint.h>

typedef unsigned short u16;
typedef _Float16 v8h __attribute__((ext_vector_type(8)));
typedef float v4f __attribute__((ext_vector_type(4)));

static __device__ __forceinline__ float h2f(u16 u) {
    union { u16 s; _Float16 h; } v; v.s = u; return (float)v.h;
}
static __device__ __forceinline__ u16 f2h(float f) {
    union { u16 s; _Float16 h; } v; v.h = (_Float16)f; return v.s;
}

// async global->LDS, 16B per lane. lds dest = wave-uniform base + lane*16.
static __device__ __forceinline__ void gload_lds16(const u16* g, const u16* l) {
    __builtin_amdgcn_global_load_lds(
        (const __attribute__((address_space(1))) uint32_t*)(uintptr_t)g,
        (__attribute__((address_space(3))) uint32_t*)(uintptr_t)l,
        16, 0, 0);
}

// ---------------- convert f32 -> f16, vectorized x8 ----------------
__global__ __launch_bounds__(256) void cvt_f16(const float* __restrict__ in,
                                               u16* __restrict__ out, int n8) {
    const int i = blockIdx.x * 256 + threadIdx.x;
    if (i >= n8) return;
    const float4 a = ((const float4*)in)[2 * i];
    const float4 b = ((const float4*)in)[2 * i + 1];
    u16 o[8] = {f2h(a.x), f2h(a.y), f2h(a.z), f2h(a.w),
                f2h(b.x), f2h(b.y), f2h(b.z), f2h(b.w)};
    *(uint4*)(out + (size_t)i * 8) = *(const uint4*)o;
}

// ---------------- all weight transposes f32 [R][C] -> f16 [C][R], one launch ----------------
__global__ __launch_bounds__(256) void transpose_all(
    const float* __restrict__ Wq, const float* __restrict__ Wk,
    const float* __restrict__ Wv, const float* __restrict__ Wo,
    const float* __restrict__ W1, const float* __restrict__ W2,
    u16* __restrict__ WqkvT, u16* __restrict__ WoT,
    u16* __restrict__ W1T, u16* __restrict__ W2T)
{
    int t = blockIdx.x;
    const float* in; u16* out; long ldi, ldo; int xt;
    if (t < 1024)      {            in = Wq; out = WqkvT;               ldi = 1024; ldo = 1024; xt = 32; }
    else if (t < 2048) { t -= 1024; in = Wk; out = WqkvT + 1024*1024;   ldi = 1024; ldo = 1024; xt = 32; }
    else if (t < 3072) { t -= 2048; in = Wv; out = WqkvT + 2*1024*1024; ldi = 1024; ldo = 1024; xt = 32; }
    else if (t < 4096) { t -= 3072; in = Wo; out = WoT;                 ldi = 1024; ldo = 1024; xt = 32; }
    else if (t < 8192) { t -= 4096; in = W1; out = W1T;                 ldi = 4096; ldo = 1024; xt = 128; }
    else               { t -= 8192; in = W2; out = W2T;                 ldi = 1024; ldo = 4096; xt = 32; }
    const int c0 = (t % xt) * 32, r0 = (t / xt) * 32;
    __shared__ float tile[32][33];
    for (int i = threadIdx.y; i < 32; i += 8)
        tile[i][threadIdx.x] = in[(long)(r0 + i) * ldi + c0 + threadIdx.x];
    __syncthreads();
    for (int i = threadIdx.y; i < 32; i += 8)
        out[(long)(c0 + i) * ldo + r0 + threadIdx.x] = f2h(tile[threadIdx.x][i]);
}

// ======== f16 GEMM: C = A @ B^T (+bias)(+relu) ========
// OMODE: 0 = f16 out
//        3 = QKV mode: n0<2048 -> normal f16 write to C0 (ldc); n0>=2048 -> transposed
//            batched write to C1: C1[b][col-2048][row], b = m0>>11 (batch rows 2048)
// BIAS: 0 none, 1 single, 3 triple (col>>10 selects bias/bias2/bias3)
// NX/NY/NZ: compile-time grid dims. XCD Y-band remap: each XCD (lin%8) gets a
// contiguous band of (NY*NZ/8) Y-tiles across all x -> A fetched once per device,
// B streamed with k-slab reuse inside the band. Bit-identical math.
// BK=64, XOR-swizzled LDS (conflict-free), 32 MFMA per barrier-pair.
template<int OMODE, int BIAS, bool RELU, int NX, int NY, int NZ>
__global__ __launch_bounds__(256) void gemm_f16(
    const u16* __restrict__ A, long lda, long Asb,
    const u16* __restrict__ B, long ldb, long Bsb,
    void* __restrict__ Cv, long ldc, long Csb, u16* __restrict__ C1,
    const float* __restrict__ bias, const float* __restrict__ bias2,
    const float* __restrict__ bias3, int K)
{
    static_assert((NY * NZ) % 8 == 0, "Y-band remap needs NY*NZ % 8 == 0");
    alignas(16) __shared__ u16 As[128 * 64];
    alignas(16) __shared__ u16 Bs[128 * 64];
    const int t = threadIdx.x;

    // ---- XCD Y-band remap (compile-time div/mod) ----
    const int lin = blockIdx.x + NX * (blockIdx.y + NY * blockIdx.z);
    const int g = lin & 7;
    const int s = lin >> 3;
    const int xe = s % NX;
    const int yl = s / NX;
    const int Y = g * (NY * NZ / 8) + yl;
    const int ye = Y % NY;
    const long b = Y / NY;

    A += b * Asb; B += b * Bsb;
    const long m0 = (long)ye * 128;
    const long n0 = (long)xe * 128;
    const int lane = t & 63, wave = t >> 6;
    const int wm = (wave >> 1) * 64, wn = (wave & 1) * 64;
    const int l16 = lane & 15, quad = lane >> 4;

    const int rr = t >> 3;                           // 0..31
    const int cg8 = ((t & 7) ^ ((t >> 3) & 7)) * 8;  // lane-permuted col (elts)
    const int wv512 = wave * 512;

    // hoisted per-thread global element offsets (k0 stays uniform/scalar)
    long aofs[4], bofs[4];
#pragma unroll
    for (int p = 0; p < 4; ++p) {
        aofs[p] = (m0 + p * 32 + rr) * lda + cg8;
        bofs[p] = (n0 + p * 32 + rr) * ldb + cg8;
    }

    v4f acc[4][4];
#pragma unroll
    for (int i = 0; i < 4; ++i)
#pragma unroll
        for (int j = 0; j < 4; ++j)
            acc[i][j] = (v4f){0.f, 0.f, 0.f, 0.f};

    for (int k0 = 0; k0 < K; k0 += 64) {
        __syncthreads();
#pragma unroll
        for (int p = 0; p < 4; ++p) {
            gload_lds16(A + aofs[p] + k0, As + p * 2048 + wv512);
            gload_lds16(B + bofs[p] + k0, Bs + p * 2048 + wv512);
        }
        __syncthreads();

#pragma unroll
        for (int kk = 0; kk < 2; ++kk) {
            const int swz = ((kk * 4 + quad) ^ (l16 & 7)) * 8;
            v8h af[4], bfr[4];
#pragma unroll
            for (int i = 0; i < 4; ++i)
                af[i] = *(const v8h*)&As[(wm + i * 16 + l16) * 64 + swz];
#pragma unroll
            for (int j = 0; j < 4; ++j)
                bfr[j] = *(const v8h*)&Bs[(wn + j * 16 + l16) * 64 + swz];
#pragma unroll
            for (int i = 0; i < 4; ++i)
#pragma unroll
                for (int j = 0; j < 4; ++j)
                    acc[i][j] = __builtin_amdgcn_mfma_f32_16x16x32_f16(af[i], bfr[j], acc[i][j], 0, 0, 0);
        }
    }

    // per-j bias
    float bv[4];
#pragma unroll
    for (int j = 0; j < 4; ++j) {
        const long col = n0 + wn + j * 16 + l16;
        if (BIAS == 0) bv[j] = 0.f;
        else if (BIAS == 1) bv[j] = bias[col];
        else {
            const int sel = (int)(col >> 10);
            const float* bp = sel == 0 ? bias : (sel == 1 ? bias2 : bias3);
            bv[j] = bp[col & 1023];
        }
    }

    if (OMODE == 3 && n0 >= 2048) {
        // transposed write: C1[b][col-2048][row], batch from m0 (batch rows = 2048)
        const long bb = m0 >> 11, mb = m0 & 2047;
        u16* C = C1 + bb * Csb;
#pragma unroll
        for (int j = 0; j < 4; ++j) {
            const long col = n0 - 2048 + wn + j * 16 + l16;
            u16* pc = C + col * 2048 + mb + wm + quad * 4;
#pragma unroll
            for (int i = 0; i < 4; ++i) {
                u16 o[4];
#pragma unroll
                for (int r = 0; r < 4; ++r) {
                    float val = acc[i][j][r] + bv[j];
                    if (RELU) val = fmaxf(val, 0.f);
                    o[r] = f2h(val);
                }
                *(uint2*)(pc + i * 16) = *(const uint2*)o;
            }
        }
    } else {
        const long cb = b * ((OMODE == 3) ? 0 : Csb) + (m0 + wm + quad * 4) * ldc + (n0 + wn + l16);
        u16* p0 = (u16*)Cv + cb;
#pragma unroll
        for (int i = 0; i < 4; ++i)
#pragma unroll
            for (int r = 0; r < 4; ++r) {
                u16* prow = p0 + (long)(i * 16 + r) * ldc;
#pragma unroll
                for (int j = 0; j < 4; ++j) {
                    float val = acc[i][j][r] + bv[j];
                    if (RELU) val = fmaxf(val, 0.f);
                    prow[j * 16] = f2h(val);
                }
            }
    }
}

// ---------------- softmax over f16 rows of 2048, in place ----------------
__global__ __launch_bounds__(256) void softmax_rows(u16* __restrict__ S) {
    const long row = blockIdx.x;
    u16* p = S + row * 2048;
    const int t = threadIdx.x;
    float v[8];
    float mx = -1e30f;
#pragma unroll
    for (int i = 0; i < 8; ++i) { v[i] = h2f(p[t + i * 256]); mx = fmaxf(mx, v[i]); }
    __shared__ float red[256];
    red[t] = mx; __syncthreads();
    for (int off = 128; off > 0; off >>= 1) {
        if (t < off) red[t] = fmaxf(red[t], red[t + off]);
        __syncthreads();
    }
    mx = red[0]; __syncthreads();
    float sum = 0.f;
#pragma unroll
    for (int i = 0; i < 8; ++i) { v[i] = __expf(v[i] - mx); sum += v[i]; }
    red[t] = sum; __syncthreads();
    for (int off = 128; off > 0; off >>= 1) {
        if (t < off) red[t] += red[t + off];
        __syncthreads();
    }
    const float inv = 1.f / red[0];
#pragma unroll
    for (int i = 0; i < 8; ++i) p[t + i * 256] = f2h(v[i] * inv);
}

// ---------------- ln1: xh_f16 = LN(src_f32 + attnO_f16) ----------------
__global__ __launch_bounds__(256) void ln_one(
    const float* __restrict__ a, const u16* __restrict__ bb,
    const float* __restrict__ g, const float* __restrict__ be,
    u16* __restrict__ out16)
{
    const long base = (long)blockIdx.x * 1024;
    const int t = threadIdx.x;
    float v[4]; float s = 0.f, ss = 0.f;
#pragma unroll
    for (int i = 0; i < 4; ++i) {
        const int c = t + i * 256;
        const float x = a[base + c] + h2f(bb[base + c]);
        v[i] = x; s += x; ss += x * x;
    }
    __shared__ float rs[256], rss[256];
    rs[t] = s; rss[t] = ss; __syncthreads();
    for (int off = 128; off > 0; off >>= 1) {
        if (t < off) { rs[t] += rs[t + off]; rss[t] += rss[t + off]; }
        __syncthreads();
    }
    const float mean = rs[0] * (1.f / 1024.f);
    const float var = rss[0] * (1.f / 1024.f) - mean * mean;
    const float rstd = rsqrtf(var + 1e-5f);
#pragma unroll
    for (int i = 0; i < 4; ++i) {
        const int c = t + i * 256;
        out16[base + c] = f2h((v[i] - mean) * rstd * g[c] + be[c]);
    }
}

// ---------------- ln2: out_f32 = LN(xh_f16 + ffO_f16) ----------------
__global__ __launch_bounds__(256) void ln_two(
    const u16* __restrict__ a, const u16* __restrict__ bb,
    const float* __restrict__ g, const float* __restrict__ be,
    float* __restrict__ out)
{
    const long base = (long)blockIdx.x * 1024;
    const int t = threadIdx.x;
    float v[4]; float s = 0.f, ss = 0.f;
#pragma unroll
    for (int i = 0; i < 4; ++i) {
        const int c = t + i * 256;
        const float x = h2f(a[base + c]) + h2f(bb[base + c]);
        v[i] = x; s += x; ss += x * x;
    }
    __shared__ float rs[256], rss[256];
    rs[t] = s; rss[t] = ss; __syncthreads();
    for (int off = 128; off > 0; off >>= 1) {
        if (t < off) { rs[t] += rs[t + off]; rss[t] += rss[t + off]; }
        __syncthreads();
    }
    const float mean = rs[0] * (1.f / 1024.f);
    const float var = rss[0] * (1.f / 1024.f) - mean * mean;
    const float rstd = rsqrtf(var + 1e-5f);
#pragma unroll
    for (int i = 0; i < 4; ++i) {
        const int c = t + i * 256;
        out[base + c] = (v[i] - mean) * rstd * g[c] + be[c];
    }
}

extern "C" void kernel_launch(void* const* d_in, const int* in_sizes, int n_in,
                              void* d_out, int out_size, void* d_ws, size_t ws_size,
                              hipStream_t stream) {
    (void)in_sizes; (void)n_in; (void)out_size; (void)ws_size;
    constexpr long S = 2048, E = 1024, F = 4096, M = 8192;

    const float* src = (const float*)d_in[0];
    const float* Wq  = (const float*)d_in[1];
    const float* bq  = (const float*)d_in[2];
    const float* Wk  = (const float*)d_in[3];
    const float* bk  = (const float*)d_in[4];
    const float* Wv  = (const float*)d_in[5];
    const float* bv  = (const float*)d_in[6];
    const float* Wo  = (const float*)d_in[7];
    const float* bo  = (const float*)d_in[8];
    const float* W1  = (const float*)d_in[9];
    const float* b1  = (const float*)d_in[10];
    const float* W2  = (const float*)d_in[11];
    const float* b2  = (const float*)d_in[12];
    const float* g1  = (const float*)d_in[13];
    const float* be1 = (const float*)d_in[14];
    const float* g2  = (const float*)d_in[15];
    const float* be2 = (const float*)d_in[16];

    char* ws = (char*)d_ws;
    size_t off = 0;
    auto take = [&](size_t bytes) {
        char* p = ws + off;
        off += (bytes + 255) & ~(size_t)255;
        return p;
    };
    const size_t MB16 = 16777216;  // f16 [8192][1024]
    u16*   srcH  = (u16*)take(MB16);
    u16*   WqkvT = (u16*)take(3 * E * E * 2);     // [3072][1024]: WqT | WkT | WvT
    u16*   WoT   = (u16*)take(E * E * 2);
    u16*   W1T   = (u16*)take(F * E * 2);         // [4096][1024]
    u16*   W2T   = (u16*)take(E * F * 2);         // [1024][4096]
    char*  B0    = take(2 * MB16);                // QK f16 [8192][2048]
    char*  B1    = take(MB16);                    // VT f16 [4][1024][2048]
    char*  B2    = take(4ull * S * S * 4);        // Sh f16 (32M) -> hf f16 [8192][4096] (64M)
    char*  B3    = take(MB16);                    // attn f16 -> xh f16
    char*  B4    = take(MB16);                    // attnO f16 -> ffO f16

    u16*   QK    = (u16*)B0;
    u16*   VT    = (u16*)B1;
    u16*   Sh    = (u16*)B2;
    u16*   hf    = (u16*)B2;
    u16*   attn  = (u16*)B3;
    u16*   xh    = (u16*)B3;
    u16*   attnO = (u16*)B4;
    u16*   ffO   = (u16*)B4;

    dim3 blk(256), tb(32, 8);

    // 1) convert src -> f16
    cvt_f16<<<dim3(M * E / 8 / 256), blk, 0, stream>>>(src, srcH, M * E / 8);

    // 2) all weight transposes in one launch
    transpose_all<<<dim3(12288), tb, 0, stream>>>(Wq, Wk, Wv, Wo, W1, W2,
                                                  WqkvT, WoT, W1T, W2T);

    // 3) merged Q|K|V projection: QK [8192][2048] f16 + VT[b][col][row] (1536 blocks)
    gemm_f16<3, 3, false, 24, 64, 1><<<dim3(24, 64, 1), blk, 0, stream>>>(
        srcH, E, 0, WqkvT, E, 0, QK, 2 * E, E * S, VT, bq, bk, bv, E);

    // 4) scores[b] = Q[b] @ K[b]^T (f16 out, ld 2048)
    gemm_f16<0, 0, false, 16, 16, 4><<<dim3(16, 16, 4), blk, 0, stream>>>(
        QK, 2 * E, S * 2 * E, QK + E, 2 * E, S * 2 * E,
        Sh, S, S * S, nullptr, nullptr, nullptr, nullptr, E);

    // 5) softmax in place (f16)
    softmax_rows<<<dim3(M), blk, 0, stream>>>(Sh);

    // 6) attn[b] = P[b] @ V[b]
    gemm_f16<0, 0, false, 8, 16, 4><<<dim3(8, 16, 4), blk, 0, stream>>>(
        Sh, S, S * S, VT, S, E * S,
        attn, E, S * E, nullptr, nullptr, nullptr, nullptr, S);

    // 7) attnO = attn @ Wo + bo (f16)
    gemm_f16<0, 1, false, 8, 64, 1><<<dim3(8, 64, 1), blk, 0, stream>>>(
        attn, E, 0, WoT, E, 0, attnO, E, 0, nullptr, bo, nullptr, nullptr, E);

    // 8) xh = LN(src + attnO) (f16, over dead attn)
    ln_one<<<dim3(M), blk, 0, stream>>>(src, attnO, g1, be1, xh);

    // 9) hf = relu(xh @ W1 + b1) (f16, over dead Sh/P)
    gemm_f16<0, 1, true, 32, 64, 1><<<dim3(32, 64, 1), blk, 0, stream>>>(
        xh, E, 0, W1T, E, 0, hf, F, 0, nullptr, b1, nullptr, nullptr, E);

    // 10) ffO = hf @ W2 + b2 (f16, over dead attnO)
    gemm_f16<0, 1, false, 8, 64, 1><<<dim3(8, 64, 1), blk, 0, stream>>>(
        hf, F, 0, W2T, F, 0, ffO, E, 0, nullptr, b2, nullptr, nullptr, F);

    // 11) out = LN(xh + ffO) -> f32
    ln_two<<<dim3(M), blk, 0, stream>>>(xh, ffO, g2, be2, (float*)d_out);
}